// Round 21
// baseline (533.276 us; speedup 1.0000x reference)
//
#include <hip/hip_runtime.h>
#include <stdint.h>

#define B_ 2
#define T_ 2048
#define P_ 1024
#define H_ 16
#define D_ 128
#define C_ 2048
#define S_ 3072   // P_ + T_
#define M_ 4096   // B_*T_
#define N3_ 6144  // 3*C_

typedef unsigned short u16;
typedef unsigned int uint32;
typedef __attribute__((ext_vector_type(8))) short short8;
typedef __attribute__((ext_vector_type(8))) __bf16 bf16x8;
typedef __attribute__((ext_vector_type(4))) float f32x4;
typedef __attribute__((ext_vector_type(16))) float f32x16;
typedef __attribute__((ext_vector_type(4))) unsigned short u16x4;
typedef __attribute__((ext_vector_type(4))) unsigned int uint4v;

#define SL2_ 0.12755883f   // (1/sqrt(128)) * log2(e), folded into Q at RoPE

static __device__ __forceinline__ float bf2f(u16 h) {
    union { unsigned int u; float f; } x; x.u = ((unsigned int)h) << 16; return x.f;
}
static __device__ __forceinline__ u16 f2bf(float f) {
    return __builtin_bit_cast(u16, (__bf16)f);   // v_cvt: RNE, 1 op
}
static __device__ __forceinline__ uint32 cvtpk(float lo, float hi) {
    uint32 r;                                    // D[15:0]=bf16(S0), D[31:16]=bf16(S1)
    asm("v_cvt_pk_bf16_f32 %0, %1, %2" : "=v"(r) : "v"(lo), "v"(hi));
    return r;
}

static __device__ __forceinline__ f32x4 mfma_bf16(short8 a, short8 b, f32x4 c) {
    return __builtin_amdgcn_mfma_f32_16x16x32_bf16(
        __builtin_bit_cast(bf16x8, a), __builtin_bit_cast(bf16x8, b), c, 0, 0, 0);
}
static __device__ __forceinline__ f32x16 mfma32(short8 a, short8 b, f32x16 c) {
    return __builtin_amdgcn_mfma_f32_32x32x16_bf16(
        __builtin_bit_cast(bf16x8, a), __builtin_bit_cast(bf16x8, b), c, 0, 0, 0);
}

typedef __attribute__((address_space(3))) unsigned int lds_u32;
typedef const __attribute__((address_space(1))) unsigned int glb_u32;
static __device__ __forceinline__ void gload_lds16(const void* g, void* l) {
    __builtin_amdgcn_global_load_lds((glb_u32*)g, (lds_u32*)l, 16, 0, 0);
}

static __device__ __forceinline__ void storeC(float* p, float v) { *p = v; }
static __device__ __forceinline__ void storeC(u16* p, float v) { *p = f2bf(v); }

// V4 fragment-major layout: frag = (bh*48 + t)*16 + ks*4 + dblk, 512 u16 per
// frag; element (lane, e) = V^T[bh][d = dblk*32 + (lane&31)]
//                              [s = t*64 + ks*16 + (lane>>5)*8 + e]
// == the exact per-lane mfma32 A-fragment, so attn PV loads are coalesced
// 1KB global_load_dwordx4 (fixes R8's 64-line uncoalesced failure).

// ---------------------------------------------------------------- prep1
// Fused: castx (8192 blk) | wT qkv (3072) | wT out (1024) | rope_table (512)
// | pastk (4096) | vpastT->V4 (1024). 17920 blocks.
__global__ void __launch_bounds__(256)
prep1_kernel(const float* __restrict__ x, u16* __restrict__ Xb,
             const float* __restrict__ w_qkv, u16* __restrict__ Wqkvt,
             const float* __restrict__ w_out, u16* __restrict__ Woutt,
             float* __restrict__ cosT, float* __restrict__ sinT,
             const float* __restrict__ past_k, u16* __restrict__ Kc,
             const float* __restrict__ past_v, u16* __restrict__ V4) {
    __shared__ __align__(16) char smem[16640];
    const int bid = blockIdx.x, tid = threadIdx.x;

    if (bid < 8192) {                                  // ---- castx
        int idx = bid * 256 + tid;
        const float4 v = ((const float4*)x)[idx];
        u16x4 o;
        o.x = f2bf(v.x); o.y = f2bf(v.y); o.z = f2bf(v.z); o.w = f2bf(v.w);
        ((u16x4*)Xb)[idx] = o;
    } else if (bid < 12288) {                          // ---- wT (both weights)
        const float* W; u16* Wt; int Ndim, n0, k0;
        if (bid < 11264) {
            int t = bid - 8192;                        // grid (96, 32)
            W = w_qkv; Wt = Wqkvt; Ndim = N3_;
            n0 = (t % 96) * 64; k0 = (t / 96) * 64;
        } else {
            int t = bid - 11264;                       // grid (32, 32)
            W = w_out; Wt = Woutt; Ndim = C_;
            n0 = (t & 31) * 64; k0 = (t >> 5) * 64;
        }
        float (*tile)[65] = (float(*)[65])smem;
#pragma unroll
        for (int i = 0; i < 16; i++) {
            int idx = tid + i * 256;
            int r = idx >> 6, c = idx & 63;            // r: k, c: n
            tile[r][c] = W[(size_t)(k0 + r) * Ndim + n0 + c];
        }
        __syncthreads();
#pragma unroll
        for (int i = 0; i < 16; i++) {
            int idx = tid + i * 256;
            int r = idx >> 6, c = idx & 63;            // r: n, c: k
            Wt[(size_t)(n0 + r) * C_ + k0 + c] = f2bf(tile[c][r]);
        }
    } else if (bid < 12800) {                          // ---- rope_table
        int idx = (bid - 12288) * 256 + tid;           // T_*64
        int t = idx >> 6, d = idx & 63;
        float inv = powf(10000.0f, -(float)d * (1.0f / 64.0f));
        float ang = (float)(P_ + t) * inv;
        cosT[idx] = cosf(ang);
        sinT[idx] = sinf(ang);
    } else if (bid < 16896) {                          // ---- pastk (vec x4)
        int idx = (bid - 12800) * 256 + tid;
        int d4 = idx & 31;
        int p = (idx >> 5) & 1023;
        int bh = idx >> 15;
        const float4 v = ((const float4*)past_k)[idx];
        u16x4 o;
        o.x = f2bf(v.x); o.y = f2bf(v.y); o.z = f2bf(v.z); o.w = f2bf(v.w);
        *(u16x4*)&Kc[((size_t)bh * S_ + p) * 128 + (d4 << 2)] = o;
    } else {                                           // ---- vpastT -> V4
        int t = bid - 16896;                           // grid (16, 2, 32)
        const int p0 = (t & 15) * 64, d0 = ((t >> 4) & 1) * 64, bh = t >> 5;
        float (*tile)[65] = (float(*)[65])smem;
#pragma unroll
        for (int i = 0; i < 16; i++) {
            int idx = tid + i * 256;
            int r = idx >> 6, c = idx & 63;            // r: p, c: d
            tile[r][c] = past_v[((size_t)bh * P_ + p0 + r) * 128 + d0 + c];
        }
        __syncthreads();
        const int t_tile = p0 >> 6;                    // 0..15
#pragma unroll
        for (int i = 0; i < 2; i++) {
            int idx = tid + i * 256;                   // 0..511
            int dl = idx >> 3, c8 = idx & 7;
            int d = d0 + dl;
            int ks = c8 >> 1, h2 = c8 & 1;
            size_t frag = ((size_t)(bh * 48 + t_tile) * 16 + ks * 4 + (d >> 5));
            u16* dst = V4 + frag * 512 + ((h2 << 5) + (d & 31)) * 8;
            u16x4 lo, hh;
#pragma unroll
            for (int e = 0; e < 4; e++) {
                lo[e] = f2bf(tile[c8 * 8 + e][dl]);
                hh[e] = f2bf(tile[c8 * 8 + 4 + e][dl]);
            }
            *(u16x4*)dst = lo;
            *(u16x4*)(dst + 4) = hh;
        }
    }
}

// ---------------------------------------------------------------- prep2
// Fused: rope_qk (4096 blk) | vnewT->V4 (2048 blk). Total 6144 blocks.
__global__ void __launch_bounds__(256)
prep2_kernel(u16* __restrict__ QKVb, u16* __restrict__ Kc,
             const float* __restrict__ cosT, const float* __restrict__ sinT,
             u16* __restrict__ V4) {
    __shared__ u16 tile[64][65];
    const int bid = blockIdx.x, tid = threadIdx.x;

    if (bid < 4096) {                                  // ---- rope_qk (vec x4)
        int idx = bid * 256 + tid;                     // B_*T_*H_*16 = 1048576
        int j = idx & 15;                              // d quad
        int h = (idx >> 4) & 15;
        int t = (idx >> 8) & 2047;
        int b = idx >> 19;
        const int d0 = j << 2;
        size_t rowoff = (size_t)(b * T_ + t) * N3_;
        const float4 cv = *(const float4*)&cosT[(t << 6) + d0];
        const float4 sv = *(const float4*)&sinT[(t << 6) + d0];
        const float cc[4] = {cv.x, cv.y, cv.z, cv.w};
        const float ss[4] = {sv.x, sv.y, sv.z, sv.w};
        {   // Q (scaled by SL2_)
            u16* p = QKVb + rowoff + h * 128 + d0;
            u16x4 x1 = *(u16x4*)p, x2 = *(u16x4*)(p + 64);
            u16x4 o1, o2;
#pragma unroll
            for (int e = 0; e < 4; e++) {
                float a = bf2f(x1[e]), bb = bf2f(x2[e]);
                o1[e] = f2bf((a * cc[e] - bb * ss[e]) * SL2_);
                o2[e] = f2bf((bb * cc[e] + a * ss[e]) * SL2_);
            }
            *(u16x4*)p = o1;
            *(u16x4*)(p + 64) = o2;
        }
        {   // K -> cache (unscaled)
            const u16* p = QKVb + rowoff + C_ + h * 128 + d0;
            u16x4 x1 = *(const u16x4*)p, x2 = *(const u16x4*)(p + 64);
            u16x4 o1, o2;
#pragma unroll
            for (int e = 0; e < 4; e++) {
                float a = bf2f(x1[e]), bb = bf2f(x2[e]);
                o1[e] = f2bf(a * cc[e] - bb * ss[e]);
                o2[e] = f2bf(bb * cc[e] + a * ss[e]);
            }
            u16* o = Kc + ((size_t)(b * H_ + h) * S_ + P_ + t) * 128 + d0;
            *(u16x4*)o = o1;
            *(u16x4*)(o + 64) = o2;
        }
    } else {                                           // ---- vnewT -> V4
        int t = bid - 4096;                            // grid (32, 2, 32)
        const int t0 = (t & 31) * 64, d0 = ((t >> 5) & 1) * 64, bh = t >> 6;
        const int b = bh >> 4, h = bh & 15;
#pragma unroll
        for (int i = 0; i < 16; i++) {
            int idx = tid + i * 256;
            int r = idx >> 6, c = idx & 63;            // r: t, c: d
            tile[r][c] = QKVb[(size_t)(b * T_ + t0 + r) * N3_ + 2 * C_ + h * 128 + d0 + c];
        }
        __syncthreads();
        const int t_tile = (P_ + t0) >> 6;             // 16..47
#pragma unroll
        for (int i = 0; i < 2; i++) {
            int idx = tid + i * 256;                   // 0..511
            int dl = idx >> 3, c8 = idx & 7;
            int d = d0 + dl;
            int ks = c8 >> 1, h2 = c8 & 1;
            size_t frag = ((size_t)(bh * 48 + t_tile) * 16 + ks * 4 + (d >> 5));
            u16* dst = V4 + frag * 512 + ((h2 << 5) + (d & 31)) * 8;
            u16x4 lo, hh;
#pragma unroll
            for (int e = 0; e < 4; e++) {
                lo[e] = tile[c8 * 8 + e][dl];
                hh[e] = tile[c8 * 8 + 4 + e][dl];
            }
            *(u16x4*)dst = lo;
            *(u16x4*)(dst + 4) = hh;
        }
    }
}

// ---------------------------------------------------------------- GEMM (3-buf)
// R9 state (measured best). BM=256, BN=128, BK=64, NBUF=3 (LDS 144 KiB).
// Counted-vmcnt pipeline (T4). One barrier per K-step. XOR-swizzle via
// pre-swizzled global source (rule #21).
template <typename OutT>
__global__ void __launch_bounds__(512, 1)
gemm3(const u16* __restrict__ A, const u16* __restrict__ Bt,
      OutT* __restrict__ Co, int Mdim, int Ndim, int Kdim) {
    __shared__ u16 lA[3 * 256 * 64];   // 96 KiB
    __shared__ u16 lB[3 * 128 * 64];   // 48 KiB
    const int nbx = Ndim >> 7;
    const int nwg = (Mdim >> 8) * nbx;
    int bid = blockIdx.x;
    int wg = (bid & 7) * (nwg >> 3) + (bid >> 3);      // XCD swizzle (nwg%8==0)
    const int bm = wg / nbx, bn = wg % nbx;
    const int m0 = bm << 8, n0 = bn << 7;
    const int tid = threadIdx.x;
    const int wave = tid >> 6, lane = tid & 63;
    const int mw = wave >> 1, nw = wave & 1;
    const int l15 = lane & 15, l4 = lane >> 4;

    f32x4 acc[4][4];
#pragma unroll
    for (int i = 0; i < 4; i++)
#pragma unroll
        for (int j = 0; j < 4; j++) acc[i][j] = (f32x4){0.f, 0.f, 0.f, 0.f};

    const u16* aSrc[4];
    const u16* bSrc[2];
#pragma unroll
    for (int i = 0; i < 4; i++) {
        int cid = i * 512 + tid;
        int r = cid >> 3, pc = cid & 7;
        aSrc[i] = A + (size_t)(m0 + r) * Kdim + ((pc ^ (r & 7)) << 3);
    }
#pragma unroll
    for (int i = 0; i < 2; i++) {
        int cid = i * 512 + tid;
        int r = cid >> 3, pc = cid & 7;
        bSrc[i] = Bt + (size_t)(n0 + r) * Kdim + ((pc ^ (r & 7)) << 3);
    }

#define STAGE3(bi, kt) do {                                                     \
    u16* _pa = lA + (bi) * 16384 + wave * 512;                                  \
    u16* _pb = lB + (bi) * 8192 + wave * 512;                                   \
    _Pragma("unroll")                                                           \
    for (int i = 0; i < 4; i++)                                                 \
        gload_lds16(aSrc[i] + (size_t)(kt) * 64, _pa + i * 4096);               \
    _Pragma("unroll")                                                           \
    for (int i = 0; i < 2; i++)                                                 \
        gload_lds16(bSrc[i] + (size_t)(kt) * 64, _pb + i * 4096);               \
} while (0)

    STAGE3(0, 0);
    STAGE3(1, 1);

    const int NT = Kdim >> 6;
    int bc = 0;
    for (int t = 0; t < NT; ++t) {
        if (t + 1 < NT) asm volatile("s_waitcnt vmcnt(6)" ::: "memory");
        else            asm volatile("s_waitcnt vmcnt(0)" ::: "memory");
        __builtin_amdgcn_s_barrier();
        asm volatile("" ::: "memory");
        if (t + 2 < NT) {
            int b2 = bc + 2; if (b2 >= 3) b2 -= 3;
            STAGE3(b2, t + 2);
        }
        const u16* la = lA + bc * 16384;
        const u16* lb = lB + bc * 8192;
        short8 af[4][2], bf[4][2];
#pragma unroll
        for (int i = 0; i < 4; i++)
#pragma unroll
            for (int kk = 0; kk < 2; kk++) {
                int r = mw * 64 + i * 16 + l15;
                int cb = (kk * 64 + l4 * 16) ^ ((r & 7) << 4);
                af[i][kk] = *(const short8*)&la[r * 64 + (cb >> 1)];
            }
#pragma unroll
        for (int j = 0; j < 4; j++)
#pragma unroll
            for (int kk = 0; kk < 2; kk++) {
                int r = nw * 64 + j * 16 + l15;
                int cb = (kk * 64 + l4 * 16) ^ ((r & 7) << 4);
                bf[j][kk] = *(const short8*)&lb[r * 64 + (cb >> 1)];
            }
        __builtin_amdgcn_s_setprio(1);
#pragma unroll
        for (int kk = 0; kk < 2; kk++)
#pragma unroll
            for (int i = 0; i < 4; i++)
#pragma unroll
                for (int j = 0; j < 4; j++)
                    acc[i][j] = mfma_bf16(af[i][kk], bf[j][kk], acc[i][j]);
        __builtin_amdgcn_s_setprio(0);
        __builtin_amdgcn_sched_barrier(0);   // rule #18: pin MFMA/lgkm here
        bc = bc + 1; if (bc >= 3) bc = 0;
    }
#undef STAGE3

    // epilogue
#pragma unroll
    for (int i = 0; i < 4; i++)
#pragma unroll
        for (int j = 0; j < 4; j++) {
            int row = m0 + mw * 64 + i * 16 + (l4 << 2);
            int col = n0 + nw * 64 + j * 16 + l15;
#pragma unroll
            for (int q = 0; q < 4; q++)
                storeC(&Co[(size_t)(row + q) * Ndim + col], acc[i][j][q]);
        }
}

// ---------------------------------------------------------------- attention
// R19: V from global in fragment-major V4 layout (coalesced 1KB loads,
// double-buffered per-ks in regs) -> LDS is K-only 32 KiB -> 3 blocks/CU
// (12 waves, launch_bounds(256,3)); independent blocks desynchronize ->
// cross-block pipe overlap (m114). Denominator back to VALU partial sums
// (frees 16 VGPR). Zero bank conflicts, no-max softmax, Q pre-scaled.
__global__ void __launch_bounds__(256, 3)
attn_kernel(const u16* __restrict__ QKVb, const u16* __restrict__ Kc,
            const u16* __restrict__ V4, u16* __restrict__ O) {
    __shared__ u16 ldsK[2][64 * 128];   // 32 KiB: [buf][64 k][256B rows]

    int bid = blockIdx.x;                              // 512 blocks
    int wg = (bid & 7) * 64 + (bid >> 3);              // XCD swizzle (bijective)
    const int qc = wg & 15;                            // q-chunk (16 x 128 rows)
    const int bh = wg >> 4;
    const int b = bh >> 4, h = bh & 15;
    const int tid = threadIdx.x, wave = tid >> 6, lane = tid & 63;
    const int l31 = lane & 31, hi = lane >> 5;

    const int krow = tid >> 4;                                         // 0..15
    const int kcol = ((((tid & 15) ^ krow) << 4)) >> 1;                // u16

    const u16* Kbh = Kc + (size_t)bh * S_ * 128;
    const u16* V4l = V4 + (size_t)bh * 48 * 8192 + lane * 8;

    const int tq = qc * 128 + wave * 32 + l31;         // this lane's q row
    // Q fragments: Q[q=l31][d = ks*16 + hi*8 + e], 8 x bf16x8 (pre-scaled)
    short8 qf[8];
    {
        const u16* qp = QKVb + (size_t)(b * T_ + tq) * N3_ + h * 128 + hi * 8;
#pragma unroll
        for (int ks = 0; ks < 8; ks++) qf[ks] = *(const short8*)(qp + ks * 16);
    }

    f32x16 acco[4];                                    // O^T: col q=l31, row d
#pragma unroll
    for (int d = 0; d < 4; d++) acco[d] = (f32x16)(0.0f);
    float lrow = 0.f;

#define STAGEK(bufi, tt) do {                                                   \
    const int _s0 = (tt) * 64;                                                  \
    _Pragma("unroll")                                                           \
    for (int i = 0; i < 4; i++)                                                 \
        gload_lds16(Kbh + (size_t)(_s0 + krow + i * 16) * 128 + kcol,           \
                    (char*)&ldsK[bufi][0] + i * 4096 + wave * 1024);            \
} while (0)

    STAGEK(0, 0);
    __syncthreads();

    const int swzK = (l31 & 15) << 4;                  // K read swizzle (bytes)

    for (int t = 0; t < S_ / 64; ++t) {
        const int cur = t & 1;
        const u16* ft = V4l + t * 8192;                // this tile's frags

        // issue ks=0 V frags early (drain under QK^T)
        short8 va[4], vb[4];
#pragma unroll
        for (int dblk = 0; dblk < 4; dblk++)
            va[dblk] = *(const short8*)(ft + dblk * 512);

        if (t < S_ / 64 - 1) STAGEK(cur ^ 1, t + 1);

        const u16* Kl = &ldsK[cur][0];

        // ---- QK^T: p0 (k 0..31), p1 (k 32..63); contraction d ----
        f32x16 p0 = (f32x16)(0.0f), p1 = (f32x16)(0.0f);
        __builtin_amdgcn_s_setprio(1);
#pragma unroll
        for (int ks = 0; ks < 8; ks++) {
            const int cidx = (((ks * 32 + hi * 16) ^ swzK) >> 1);
            short8 k0 = *(const short8*)&Kl[(l31 << 7) + cidx];
            short8 k1 = *(const short8*)&Kl[((32 + l31) << 7) + cidx];
            p0 = mfma32(k0, qf[ks], p0);
            p1 = mfma32(k1, qf[ks], p1);
        }
        __builtin_amdgcn_s_setprio(0);

        // ---- P = exp2(score); denominator via 4-way partial sums ----
        float s0a = 0.f, s1a = 0.f, s2a = 0.f, s3a = 0.f;
#pragma unroll
        for (int r = 0; r < 16; r += 4) {
            p0[r + 0] = exp2f(p0[r + 0]); s0a += p0[r + 0];
            p0[r + 1] = exp2f(p0[r + 1]); s1a += p0[r + 1];
            p0[r + 2] = exp2f(p0[r + 2]); s2a += p0[r + 2];
            p0[r + 3] = exp2f(p0[r + 3]); s3a += p0[r + 3];
        }
#pragma unroll
        for (int r = 0; r < 16; r += 4) {
            p1[r + 0] = exp2f(p1[r + 0]); s0a += p1[r + 0];
            p1[r + 1] = exp2f(p1[r + 1]); s1a += p1[r + 1];
            p1[r + 2] = exp2f(p1[r + 2]); s2a += p1[r + 2];
            p1[r + 3] = exp2f(p1[r + 3]); s3a += p1[r + 3];
        }
        float sum = (s0a + s1a) + (s2a + s3a);
        sum += __shfl_xor(sum, 32);
        lrow += sum;

        // ---- P (C-layout) -> PV B-frags, in-register (T12: cvt_pk + shfl) ----
        uint32 w[4][4];
#define PACK_HALF(pp, kh, ksout) do {                                           \
    uint32 A0 = cvtpk(pp[(kh)*8 + 0], pp[(kh)*8 + 1]);                          \
    uint32 A1 = cvtpk(pp[(kh)*8 + 2], pp[(kh)*8 + 3]);                          \
    uint32 B0 = cvtpk(pp[(kh)*8 + 4], pp[(kh)*8 + 5]);                          \
    uint32 B1 = cvtpk(pp[(kh)*8 + 6], pp[(kh)*8 + 7]);                          \
    uint32 sA0 = __shfl_xor(A0, 32), sA1 = __shfl_xor(A1, 32);                  \
    uint32 sB0 = __shfl_xor(B0, 32), sB1 = __shfl_xor(B1, 32);                  \
    w[ksout][0] = hi ? sB0 : A0;                                                \
    w[ksout][1] = hi ? sB1 : A1;                                                \
    w[ksout][2] = hi ? B0 : sA0;                                                \
    w[ksout][3] = hi ? B1 : sA1;                                                \
} while (0)
        PACK_HALF(p0, 0, 0);
        PACK_HALF(p0, 1, 1);
        PACK_HALF(p1, 0, 2);
        PACK_HALF(p1, 1, 3);
#undef PACK_HALF

        // ---- PV: O^T[d][q] += V^T[d][k] * P^T[k][q]; V regs dbl-buffered ----
        __builtin_amdgcn_s_setprio(1);
        {
            // ks = 0 (va live); prefetch ks=1 into vb
#pragma unroll
            for (int dblk = 0; dblk < 4; dblk++)
                vb[dblk] = *(const short8*)(ft + (4 + dblk) * 512);
            uint4v pw0 = {w[0][0], w[0][1], w[0][2], w[0][3]};
            short8 pf0 = __builtin_bit_cast(short8, pw0);
#pragma unroll
            for (int dblk = 0; dblk < 4; dblk++)
                acco[dblk] = mfma32(va[dblk], pf0, acco[dblk]);
            // ks = 1 (vb); prefetch ks=2 into va
#pragma unroll
            for (int dblk = 0; dblk < 4; dblk++)
                va[dblk] = *(const short8*)(ft + (8 + dblk) * 512);
            uint4v pw1 = {w[1][0], w[1][1], w[1][2], w[1][3]};
            short8 pf1 = __builtin_bit_cast(short8, pw1);
#pragma unroll
            for (int dblk = 0; dblk < 4; dblk++)
                acco[dblk] = mfma32(vb[dblk], pf1, acco[dblk]);
            // ks = 2 (va); prefetch ks=3 into vb
#pragma unroll
            for (int dblk = 0; dblk < 4; dblk++)
                vb[dblk] = *(const short8*)(ft + (12 + dblk) * 512);
            uint4v pw2 = {w[2][0], w[2][1], w[2][2], w[2][3]};
            short8 pf2 = __builtin_bit_cast(short8, pw2);
#pragma unroll
            for (int dblk = 0; dblk < 4; dblk++)
                acco[dblk] = mfma32(va[dblk], pf2, acco[dblk]);
            // ks = 3 (vb)
            uint4v pw3 = {w[3][0], w[3][1], w[3][2], w[3][3]};
            short8 pf3 = __builtin_bit_cast(short8, pw3);
#pragma unroll
            for (int dblk = 0; dblk < 4; dblk++)
                acco[dblk] = mfma32(vb[dblk], pf3, acco[dblk]);
        }
        __builtin_amdgcn_s_setprio(0);

        __syncthreads();   // readers done with K[cur]; STAGEK(cur^1) drained
    }
#undef STAGEK

    // ---- epilogue: O[b*T+tq][h*128+d], d = dblk*32 + 8*j + 4*hi + {0..3} ----
    float rl = 1.0f / lrow;
    u16* Op = O + (size_t)(b * T_ + tq) * C_ + h * 128;
#pragma unroll
    for (int dblk = 0; dblk < 4; dblk++)
#pragma unroll
        for (int j = 0; j < 4; j++) {
            u16x4 o;
            o.x = f2bf(acco[dblk][4 * j + 0] * rl);
            o.y = f2bf(acco[dblk][4 * j + 1] * rl);
            o.z = f2bf(acco[dblk][4 * j + 2] * rl);
            o.w = f2bf(acco[dblk][4 * j + 3] * rl);
            *(u16x4*)(Op + dblk * 32 + j * 8 + hi * 4) = o;
        }
}

// ---------------------------------------------------------------- launch

extern "C" void kernel_launch(void* const* d_in, const int* in_sizes, int n_in,
                              void* d_out, int out_size, void* d_ws, size_t ws_size,
                              hipStream_t stream) {
    const float* x      = (const float*)d_in[0];
    const float* w_qkv  = (const float*)d_in[1];
    const float* w_out  = (const float*)d_in[2];
    const float* past_k = (const float*)d_in[3];
    const float* past_v = (const float*)d_in[4];
    float* out = (float*)d_out;

    char* ws = (char*)d_ws;
    u16* Xb    = (u16*)(ws);                            // 16 MB
    u16* Wqkvt = (u16*)(ws + 16777216);                 // 24 MB
    u16* Woutt = (u16*)(ws + 41943040);                 //  8 MB
    u16* QKVb  = (u16*)(ws + 50331648);                 // 48 MB
    u16* Kc    = (u16*)(ws + 100663296);                // 24 MB
    u16* V4    = (u16*)(ws + 125829120);                // 24 MB (fragment-major)
    u16* O     = (u16*)(ws + 150994944);                // 16 MB
    float* cosT = (float*)(ws + 167772160);             // 0.5 MB
    float* sinT = (float*)(ws + 168296448);             // 0.5 MB

    prep1_kernel<<<17920, 256, 0, stream>>>(x, Xb, w_qkv, Wqkvt, w_out, Woutt,
                                            cosT, sinT, past_k, Kc, past_v, V4);

    gemm3<u16><<<(M_ / 256) * (N3_ / 128), 512, 0, stream>>>(Xb, Wqkvt, QKVb, M_, N3_, C_);

    prep2_kernel<<<6144, 256, 0, stream>>>(QKVb, Kc, cosT, sinT, V4);

    attn_kernel<<<512, 256, 0, stream>>>(QKVb, Kc, V4, O);

    gemm3<float><<<(M_ / 256) * (C_ / 128), 512, 0, stream>>>(O, Woutt, out, M_, C_, C_);
}

// Round 22
// 356.979 us; speedup vs baseline: 1.4939x; 1.4939x over previous
//
#include <hip/hip_runtime.h>
#include <stdint.h>

#define B_ 2
#define T_ 2048
#define P_ 1024
#define H_ 16
#define D_ 128
#define C_ 2048
#define S_ 3072   // P_ + T_
#define M_ 4096   // B_*T_
#define N3_ 6144  // 3*C_

typedef unsigned short u16;
typedef unsigned int uint32;
typedef __attribute__((ext_vector_type(8))) short short8;
typedef __attribute__((ext_vector_type(8))) __bf16 bf16x8;
typedef __attribute__((ext_vector_type(4))) float f32x4;
typedef __attribute__((ext_vector_type(16))) float f32x16;
typedef __attribute__((ext_vector_type(4))) unsigned short u16x4;
typedef __attribute__((ext_vector_type(4))) unsigned int uint4v;

#define SL2_ 0.12755883f   // (1/sqrt(128)) * log2(e), folded into Q at RoPE

static __device__ __forceinline__ float bf2f(u16 h) {
    union { unsigned int u; float f; } x; x.u = ((unsigned int)h) << 16; return x.f;
}
static __device__ __forceinline__ u16 f2bf(float f) {
    return __builtin_bit_cast(u16, (__bf16)f);   // v_cvt: RNE, 1 op
}
static __device__ __forceinline__ uint32 cvtpk(float lo, float hi) {
    uint32 r;                                    // D[15:0]=bf16(S0), D[31:16]=bf16(S1)
    asm("v_cvt_pk_bf16_f32 %0, %1, %2" : "=v"(r) : "v"(lo), "v"(hi));
    return r;
}

static __device__ __forceinline__ f32x4 mfma_bf16(short8 a, short8 b, f32x4 c) {
    return __builtin_amdgcn_mfma_f32_16x16x32_bf16(
        __builtin_bit_cast(bf16x8, a), __builtin_bit_cast(bf16x8, b), c, 0, 0, 0);
}
static __device__ __forceinline__ f32x16 mfma32(short8 a, short8 b, f32x16 c) {
    return __builtin_amdgcn_mfma_f32_32x32x16_bf16(
        __builtin_bit_cast(bf16x8, a), __builtin_bit_cast(bf16x8, b), c, 0, 0, 0);
}

typedef __attribute__((address_space(3))) unsigned int lds_u32;
typedef const __attribute__((address_space(1))) unsigned int glb_u32;
static __device__ __forceinline__ void gload_lds16(const void* g, void* l) {
    __builtin_amdgcn_global_load_lds((glb_u32*)g, (lds_u32*)l, 16, 0, 0);
}

static __device__ __forceinline__ void storeC(float* p, float v) { *p = v; }
static __device__ __forceinline__ void storeC(u16* p, float v) { *p = f2bf(v); }

// ---------------------------------------------------------------- prep1
// Fused: castx (8192 blk) | wT qkv (3072) | wT out (1024) | rope_table (512)
// | pastk (4096) | vpastT (1024). All independent of QKVb. 17920 blocks.
__global__ void __launch_bounds__(256)
prep1_kernel(const float* __restrict__ x, u16* __restrict__ Xb,
             const float* __restrict__ w_qkv, u16* __restrict__ Wqkvt,
             const float* __restrict__ w_out, u16* __restrict__ Woutt,
             float* __restrict__ cosT, float* __restrict__ sinT,
             const float* __restrict__ past_k, u16* __restrict__ Kc,
             const float* __restrict__ past_v, u16* __restrict__ Vt) {
    __shared__ __align__(16) char smem[16640];
    const int bid = blockIdx.x, tid = threadIdx.x;

    if (bid < 8192) {                                  // ---- castx
        int idx = bid * 256 + tid;
        const float4 v = ((const float4*)x)[idx];
        u16x4 o;
        o.x = f2bf(v.x); o.y = f2bf(v.y); o.z = f2bf(v.z); o.w = f2bf(v.w);
        ((u16x4*)Xb)[idx] = o;
    } else if (bid < 12288) {                          // ---- wT (both weights)
        const float* W; u16* Wt; int Ndim, n0, k0;
        if (bid < 11264) {
            int t = bid - 8192;                        // grid (96, 32)
            W = w_qkv; Wt = Wqkvt; Ndim = N3_;
            n0 = (t % 96) * 64; k0 = (t / 96) * 64;
        } else {
            int t = bid - 11264;                       // grid (32, 32)
            W = w_out; Wt = Woutt; Ndim = C_;
            n0 = (t & 31) * 64; k0 = (t >> 5) * 64;
        }
        float (*tile)[65] = (float(*)[65])smem;
#pragma unroll
        for (int i = 0; i < 16; i++) {
            int idx = tid + i * 256;
            int r = idx >> 6, c = idx & 63;            // r: k, c: n
            tile[r][c] = W[(size_t)(k0 + r) * Ndim + n0 + c];
        }
        __syncthreads();
#pragma unroll
        for (int i = 0; i < 16; i++) {
            int idx = tid + i * 256;
            int r = idx >> 6, c = idx & 63;            // r: n, c: k
            Wt[(size_t)(n0 + r) * C_ + k0 + c] = f2bf(tile[c][r]);
        }
    } else if (bid < 12800) {                          // ---- rope_table
        int idx = (bid - 12288) * 256 + tid;           // T_*64
        int t = idx >> 6, d = idx & 63;
        float inv = powf(10000.0f, -(float)d * (1.0f / 64.0f));
        float ang = (float)(P_ + t) * inv;
        cosT[idx] = cosf(ang);
        sinT[idx] = sinf(ang);
    } else if (bid < 16896) {                          // ---- pastk (vec x4)
        int idx = (bid - 12800) * 256 + tid;
        int d4 = idx & 31;
        int p = (idx >> 5) & 1023;
        int bh = idx >> 15;
        const float4 v = ((const float4*)past_k)[idx];
        u16x4 o;
        o.x = f2bf(v.x); o.y = f2bf(v.y); o.z = f2bf(v.z); o.w = f2bf(v.w);
        *(u16x4*)&Kc[((size_t)bh * S_ + p) * 128 + (d4 << 2)] = o;
    } else {                                           // ---- vpastT
        int t = bid - 16896;                           // grid (16, 2, 32)
        const int p0 = (t & 15) * 64, d0 = ((t >> 4) & 1) * 64, bh = t >> 5;
        float (*tile)[65] = (float(*)[65])smem;
#pragma unroll
        for (int i = 0; i < 16; i++) {
            int idx = tid + i * 256;
            int r = idx >> 6, c = idx & 63;            // r: p, c: d
            tile[r][c] = past_v[((size_t)bh * P_ + p0 + r) * 128 + d0 + c];
        }
        __syncthreads();
#pragma unroll
        for (int i = 0; i < 16; i++) {
            int idx = tid + i * 256;
            int r = idx >> 6, c = idx & 63;            // r: d, c: p
            Vt[((size_t)bh * 128 + d0 + r) * S_ + p0 + c] = f2bf(tile[c][r]);
        }
    }
}

// ---------------------------------------------------------------- prep2
// Fused: rope_qk (4096 blk) | vnewT (2048 blk). Total 6144 blocks.
__global__ void __launch_bounds__(256)
prep2_kernel(u16* __restrict__ QKVb, u16* __restrict__ Kc,
             const float* __restrict__ cosT, const float* __restrict__ sinT,
             u16* __restrict__ Vt) {
    __shared__ u16 tile[64][65];
    const int bid = blockIdx.x, tid = threadIdx.x;

    if (bid < 4096) {                                  // ---- rope_qk (vec x4)
        int idx = bid * 256 + tid;                     // B_*T_*H_*16 = 1048576
        int j = idx & 15;                              // d quad
        int h = (idx >> 4) & 15;
        int t = (idx >> 8) & 2047;
        int b = idx >> 19;
        const int d0 = j << 2;
        size_t rowoff = (size_t)(b * T_ + t) * N3_;
        const float4 cv = *(const float4*)&cosT[(t << 6) + d0];
        const float4 sv = *(const float4*)&sinT[(t << 6) + d0];
        const float cc[4] = {cv.x, cv.y, cv.z, cv.w};
        const float ss[4] = {sv.x, sv.y, sv.z, sv.w};
        {   // Q (scaled by SL2_)
            u16* p = QKVb + rowoff + h * 128 + d0;
            u16x4 x1 = *(u16x4*)p, x2 = *(u16x4*)(p + 64);
            u16x4 o1, o2;
#pragma unroll
            for (int e = 0; e < 4; e++) {
                float a = bf2f(x1[e]), bb = bf2f(x2[e]);
                o1[e] = f2bf((a * cc[e] - bb * ss[e]) * SL2_);
                o2[e] = f2bf((bb * cc[e] + a * ss[e]) * SL2_);
            }
            *(u16x4*)p = o1;
            *(u16x4*)(p + 64) = o2;
        }
        {   // K -> cache (unscaled)
            const u16* p = QKVb + rowoff + C_ + h * 128 + d0;
            u16x4 x1 = *(const u16x4*)p, x2 = *(const u16x4*)(p + 64);
            u16x4 o1, o2;
#pragma unroll
            for (int e = 0; e < 4; e++) {
                float a = bf2f(x1[e]), bb = bf2f(x2[e]);
                o1[e] = f2bf(a * cc[e] - bb * ss[e]);
                o2[e] = f2bf(bb * cc[e] + a * ss[e]);
            }
            u16* o = Kc + ((size_t)(b * H_ + h) * S_ + P_ + t) * 128 + d0;
            *(u16x4*)o = o1;
            *(u16x4*)(o + 64) = o2;
        }
    } else {                                           // ---- vnewT
        int t = bid - 4096;                            // grid (32, 2, 32)
        const int t0 = (t & 31) * 64, d0 = ((t >> 5) & 1) * 64, bh = t >> 6;
        const int b = bh >> 4, h = bh & 15;
#pragma unroll
        for (int i = 0; i < 16; i++) {
            int idx = tid + i * 256;
            int r = idx >> 6, c = idx & 63;            // r: t, c: d
            tile[r][c] = QKVb[(size_t)(b * T_ + t0 + r) * N3_ + 2 * C_ + h * 128 + d0 + c];
        }
        __syncthreads();
#pragma unroll
        for (int i = 0; i < 16; i++) {
            int idx = tid + i * 256;
            int r = idx >> 6, c = idx & 63;            // r: d, c: t
            Vt[((size_t)bh * 128 + d0 + r) * S_ + P_ + t0 + c] = tile[c][r];
        }
    }
}

// ---------------------------------------------------------------- GEMM (3-buf)
// R9 state (measured best). BM=256, BN=128, BK=64, NBUF=3 (LDS 144 KiB).
// 8 waves (4m x 2n), per-wave 64x64 C, 16x16x32 frags. Counted-vmcnt
// pipeline (T4). One barrier per K-step. XOR-swizzle via pre-swizzled
// global source (rule #21).
template <typename OutT>
__global__ void __launch_bounds__(512, 1)
gemm3(const u16* __restrict__ A, const u16* __restrict__ Bt,
      OutT* __restrict__ Co, int Mdim, int Ndim, int Kdim) {
    __shared__ u16 lA[3 * 256 * 64];   // 96 KiB
    __shared__ u16 lB[3 * 128 * 64];   // 48 KiB
    const int nbx = Ndim >> 7;
    const int nwg = (Mdim >> 8) * nbx;
    int bid = blockIdx.x;
    int wg = (bid & 7) * (nwg >> 3) + (bid >> 3);      // XCD swizzle (nwg%8==0)
    const int bm = wg / nbx, bn = wg % nbx;
    const int m0 = bm << 8, n0 = bn << 7;
    const int tid = threadIdx.x;
    const int wave = tid >> 6, lane = tid & 63;
    const int mw = wave >> 1, nw = wave & 1;
    const int l15 = lane & 15, l4 = lane >> 4;

    f32x4 acc[4][4];
#pragma unroll
    for (int i = 0; i < 4; i++)
#pragma unroll
        for (int j = 0; j < 4; j++) acc[i][j] = (f32x4){0.f, 0.f, 0.f, 0.f};

    const u16* aSrc[4];
    const u16* bSrc[2];
#pragma unroll
    for (int i = 0; i < 4; i++) {
        int cid = i * 512 + tid;
        int r = cid >> 3, pc = cid & 7;
        aSrc[i] = A + (size_t)(m0 + r) * Kdim + ((pc ^ (r & 7)) << 3);
    }
#pragma unroll
    for (int i = 0; i < 2; i++) {
        int cid = i * 512 + tid;
        int r = cid >> 3, pc = cid & 7;
        bSrc[i] = Bt + (size_t)(n0 + r) * Kdim + ((pc ^ (r & 7)) << 3);
    }

#define STAGE3(bi, kt) do {                                                     \
    u16* _pa = lA + (bi) * 16384 + wave * 512;                                  \
    u16* _pb = lB + (bi) * 8192 + wave * 512;                                   \
    _Pragma("unroll")                                                           \
    for (int i = 0; i < 4; i++)                                                 \
        gload_lds16(aSrc[i] + (size_t)(kt) * 64, _pa + i * 4096);               \
    _Pragma("unroll")                                                           \
    for (int i = 0; i < 2; i++)                                                 \
        gload_lds16(bSrc[i] + (size_t)(kt) * 64, _pb + i * 4096);               \
} while (0)

    STAGE3(0, 0);
    STAGE3(1, 1);

    const int NT = Kdim >> 6;
    int bc = 0;
    for (int t = 0; t < NT; ++t) {
        if (t + 1 < NT) asm volatile("s_waitcnt vmcnt(6)" ::: "memory");
        else            asm volatile("s_waitcnt vmcnt(0)" ::: "memory");
        __builtin_amdgcn_s_barrier();
        asm volatile("" ::: "memory");
        if (t + 2 < NT) {
            int b2 = bc + 2; if (b2 >= 3) b2 -= 3;
            STAGE3(b2, t + 2);
        }
        const u16* la = lA + bc * 16384;
        const u16* lb = lB + bc * 8192;
        short8 af[4][2], bf[4][2];
#pragma unroll
        for (int i = 0; i < 4; i++)
#pragma unroll
            for (int kk = 0; kk < 2; kk++) {
                int r = mw * 64 + i * 16 + l15;
                int cb = (kk * 64 + l4 * 16) ^ ((r & 7) << 4);
                af[i][kk] = *(const short8*)&la[r * 64 + (cb >> 1)];
            }
#pragma unroll
        for (int j = 0; j < 4; j++)
#pragma unroll
            for (int kk = 0; kk < 2; kk++) {
                int r = nw * 64 + j * 16 + l15;
                int cb = (kk * 64 + l4 * 16) ^ ((r & 7) << 4);
                bf[j][kk] = *(const short8*)&lb[r * 64 + (cb >> 1)];
            }
        __builtin_amdgcn_s_setprio(1);
#pragma unroll
        for (int kk = 0; kk < 2; kk++)
#pragma unroll
            for (int i = 0; i < 4; i++)
#pragma unroll
                for (int j = 0; j < 4; j++)
                    acc[i][j] = mfma_bf16(af[i][kk], bf[j][kk], acc[i][j]);
        __builtin_amdgcn_s_setprio(0);
        __builtin_amdgcn_sched_barrier(0);   // rule #18: pin MFMA/lgkm here
        bc = bc + 1; if (bc >= 3) bc = 0;
    }
#undef STAGE3

    // epilogue
#pragma unroll
    for (int i = 0; i < 4; i++)
#pragma unroll
        for (int j = 0; j < 4; j++) {
            int row = m0 + mw * 64 + i * 16 + (l4 << 2);
            int col = n0 + nw * 64 + j * 16 + l15;
#pragma unroll
            for (int q = 0; q < 4; q++)
                storeC(&Co[(size_t)(row + q) * Ndim + col], acc[i][j][q]);
        }
}

// ---------------------------------------------------------------- attention
// R20: exact revert to R18 measured-best (146.6us). T15 att[2] pairing, K
// 2-buf + V 3-buf LDS (80 KiB, 2 blocks/CU, VGPR 128 no-spill), zero bank
// conflicts, no-max softmax, ones-MFMA denominator, Q pre-scaled. R19's
// (256,3) + V-from-global spilled acco to scratch (360MB writes) - reverted.
__global__ void __launch_bounds__(256, 2)
attn_kernel(const u16* __restrict__ QKVb, const u16* __restrict__ Kc,
            const u16* __restrict__ Vt, u16* __restrict__ O) {
    __shared__ u16 ldsK[2][64 * 128];   // 32 KiB: [buf][64 k][256B rows]
    __shared__ u16 ldsV[3][64 * 128];   // 48 KiB: [buf][64 d-pair rows][256B]

    int bid = blockIdx.x;                              // 512 blocks
    int wg = (bid & 7) * 64 + (bid >> 3);              // XCD swizzle (bijective)
    const int qc = wg & 15;                            // q-chunk (16 x 128 rows)
    const int bh = wg >> 4;
    const int b = bh >> 4, h = bh & 15;
    const int tid = threadIdx.x, wave = tid >> 6, lane = tid & 63;
    const int l31 = lane & 31, hi = lane >> 5;

    // ---- staging constants (256 thr, lane-constant, dest linear) ----
    const int krow = tid >> 4;                                         // 0..15
    const int kcol = ((((tid & 15) ^ krow) << 4)) >> 1;                // u16
    const int vslog = (tid & 15) ^ (tid >> 4);
    const int vd0 = ((tid >> 4) << 1) + (vslog >> 3);                  // + i*32
    const int vk = (vslog & 7) << 3;                                   // u16

    const u16* Kbh = Kc + (size_t)bh * S_ * 128;
    const u16* Vbh = Vt + (size_t)bh * 128 * S_;

    const int tq = qc * 128 + wave * 32 + l31;         // this lane's q row
    // Q fragments: Q[q=l31][d = ks*16 + hi*8 + e], 8 x bf16x8 (pre-scaled)
    short8 qf[8];
    {
        const u16* qp = QKVb + (size_t)(b * T_ + tq) * N3_ + h * 128 + hi * 8;
#pragma unroll
        for (int ks = 0; ks < 8; ks++) qf[ks] = *(const short8*)(qp + ks * 16);
    }

    uint4v onesu = {0x3F803F80u, 0x3F803F80u, 0x3F803F80u, 0x3F803F80u};
    short8 ones8 = __builtin_bit_cast(short8, onesu);

    f32x16 acco[4];                                    // O^T: col q=l31, row d
#pragma unroll
    for (int d = 0; d < 4; d++) acco[d] = (f32x16)(0.0f);
    f32x16 accs = (f32x16)(0.0f);                      // denominator (rows equal)

    const int swzK = (l31 & 15) << 4;                  // K read swizzle (bytes)
    const int vprB = l31 >> 1;                         // V phys-row part
    const int vhbB = (l31 & 1) << 3;                   // V half-row slot base

#define STAGE(tt) do {                                                          \
    const int _s0 = (tt) * 64;                                                  \
    char* _kb = (char*)&ldsK[(tt) & 1][0];                                      \
    char* _vb = (char*)&ldsV[(tt) % 3][0];                                      \
    _Pragma("unroll")                                                           \
    for (int i = 0; i < 4; i++)                                                 \
        gload_lds16(Kbh + (size_t)(_s0 + krow + i * 16) * 128 + kcol,           \
                    _kb + i * 4096 + wave * 1024);                              \
    _Pragma("unroll")                                                           \
    for (int i = 0; i < 4; i++)                                                 \
        gload_lds16(Vbh + (size_t)(vd0 + i * 32) * S_ + _s0 + vk,               \
                    _vb + i * 4096 + wave * 1024);                              \
} while (0)

#define QKT(tt, P0, P1) do {                                                    \
    const u16* Kl = &ldsK[(tt) & 1][0];                                         \
    (P0) = (f32x16)(0.0f); (P1) = (f32x16)(0.0f);                               \
    __builtin_amdgcn_s_setprio(1);                                              \
    _Pragma("unroll")                                                           \
    for (int ks = 0; ks < 8; ks++) {                                            \
        const int cidx = (((ks * 32 + hi * 16) ^ swzK) >> 1);                   \
        short8 k0 = *(const short8*)&Kl[(l31 << 7) + cidx];                     \
        short8 k1 = *(const short8*)&Kl[((32 + l31) << 7) + cidx];              \
        (P0) = mfma32(k0, qf[ks], (P0));                                        \
        (P1) = mfma32(k1, qf[ks], (P1));                                        \
    }                                                                           \
    __builtin_amdgcn_s_setprio(0);                                              \
} while (0)

#define PACK_HALF(pp, kh, ksout, W) do {                                        \
    uint32 A0 = cvtpk(pp[(kh)*8 + 0], pp[(kh)*8 + 1]);                          \
    uint32 A1 = cvtpk(pp[(kh)*8 + 2], pp[(kh)*8 + 3]);                          \
    uint32 B0 = cvtpk(pp[(kh)*8 + 4], pp[(kh)*8 + 5]);                          \
    uint32 B1 = cvtpk(pp[(kh)*8 + 6], pp[(kh)*8 + 7]);                          \
    uint32 sA0 = __shfl_xor(A0, 32), sA1 = __shfl_xor(A1, 32);                  \
    uint32 sB0 = __shfl_xor(B0, 32), sB1 = __shfl_xor(B1, 32);                  \
    W[ksout][0] = hi ? sB0 : A0;                                                \
    W[ksout][1] = hi ? sB1 : A1;                                                \
    W[ksout][2] = hi ? B0 : sA0;                                                \
    W[ksout][3] = hi ? B1 : sA1;                                                \
} while (0)

#define SMPV(tt, P0, P1) do {                                                   \
    _Pragma("unroll")                                                           \
    for (int r = 0; r < 16; r++) (P0)[r] = exp2f((P0)[r]);                      \
    _Pragma("unroll")                                                           \
    for (int r = 0; r < 16; r++) (P1)[r] = exp2f((P1)[r]);                      \
    uint32 w[4][4];                                                             \
    PACK_HALF((P0), 0, 0, w);                                                   \
    PACK_HALF((P0), 1, 1, w);                                                   \
    PACK_HALF((P1), 0, 2, w);                                                   \
    PACK_HALF((P1), 1, 3, w);                                                   \
    const u16* Vl = &ldsV[(tt) % 3][0];                                         \
    __builtin_amdgcn_s_setprio(1);                                              \
    _Pragma("unroll")                                                           \
    for (int ks = 0; ks < 4; ks++) {                                            \
        uint4v pw = {w[ks][0], w[ks][1], w[ks][2], w[ks][3]};                   \
        short8 pf = __builtin_bit_cast(short8, pw);                             \
        _Pragma("unroll")                                                       \
        for (int dblk = 0; dblk < 4; dblk++) {                                  \
            int pr = dblk * 16 + vprB;                                          \
            int sl = (vhbB + ks * 2 + hi) ^ vprB;                               \
            short8 vf = *(const short8*)&Vl[(pr << 7) + (sl << 3)];             \
            acco[dblk] = mfma32(vf, pf, acco[dblk]);                            \
        }                                                                       \
        accs = mfma32(ones8, pf, accs);                                         \
    }                                                                           \
    __builtin_amdgcn_s_setprio(0);                                              \
} while (0)

    // ---- prologue: stage tiles 0,1; QK^T(0) ----
    STAGE(0);
    STAGE(1);
    __syncthreads();

    f32x16 pA0, pA1, pB0, pB1;
    QKT(0, pA0, pA1);

    // ---- main loop: pairs of tiles; 23 iters cover t = 0..45 ----
#pragma unroll 1
    for (int i = 0; i < 23; ++i) {
        const int t = 2 * i;
        __syncthreads();               // drains STAGE(t+1); PV(t-1) done
        STAGE(t + 2);
        QKT(t + 1, pB0, pB1);
        SMPV(t, pA0, pA1);
        __syncthreads();               // drains STAGE(t+2); PV(t) done
        STAGE(t + 3);
        QKT(t + 2, pA0, pA1);
        SMPV(t + 1, pB0, pB1);
    }
    // ---- tail: t = 46, 47 ----
    __syncthreads();                   // drains STAGE(47)
    QKT(47, pB0, pB1);
    SMPV(46, pA0, pA1);
    SMPV(47, pB0, pB1);

#undef STAGE
#undef QKT
#undef PACK_HALF
#undef SMPV

    // ---- epilogue: O[b*T+tq][h*128+d], d = dblk*32 + 8*j + 4*hi + {0..3} ----
    float rl = 1.0f / accs[0];
    u16* Op = O + (size_t)(b * T_ + tq) * C_ + h * 128;
#pragma unroll
    for (int dblk = 0; dblk < 4; dblk++)
#pragma unroll
        for (int j = 0; j < 4; j++) {
            u16x4 o;
            o.x = f2bf(acco[dblk][4 * j + 0] * rl);
            o.y = f2bf(acco[dblk][4 * j + 1] * rl);
            o.z = f2bf(acco[dblk][4 * j + 2] * rl);
            o.w = f2bf(acco[dblk][4 * j + 3] * rl);
            *(u16x4*)(Op + dblk * 32 + j * 8 + hi * 4) = o;
        }
}

// ---------------------------------------------------------------- launch

extern "C" void kernel_launch(void* const* d_in, const int* in_sizes, int n_in,
                              void* d_out, int out_size, void* d_ws, size_t ws_size,
                              hipStream_t stream) {
    const float* x      = (const float*)d_in[0];
    const float* w_qkv  = (const float*)d_in[1];
    const float* w_out  = (const float*)d_in[2];
    const float* past_k = (const float*)d_in[3];
    const float* past_v = (const float*)d_in[4];
    float* out = (float*)d_out;

    char* ws = (char*)d_ws;
    u16* Xb    = (u16*)(ws);                            // 16 MB
    u16* Wqkvt = (u16*)(ws + 16777216);                 // 24 MB
    u16* Woutt = (u16*)(ws + 41943040);                 //  8 MB
    u16* QKVb  = (u16*)(ws + 50331648);                 // 48 MB
    u16* Kc    = (u16*)(ws + 100663296);                // 24 MB
    u16* Vt    = (u16*)(ws + 125829120);                // 24 MB
    u16* O     = (u16*)(ws + 150994944);                // 16 MB
    float* cosT = (float*)(ws + 167772160);             // 0.5 MB
    float* sinT = (float*)(ws + 168296448);             // 0.5 MB

    prep1_kernel<<<17920, 256, 0, stream>>>(x, Xb, w_qkv, Wqkvt, w_out, Woutt,
                                            cosT, sinT, past_k, Kc, past_v, Vt);

    gemm3<u16><<<(M_ / 256) * (N3_ / 128), 512, 0, stream>>>(Xb, Wqkvt, QKVb, M_, N3_, C_);

    prep2_kernel<<<6144, 256, 0, stream>>>(QKVb, Kc, cosT, sinT, Vt);

    attn_kernel<<<512, 256, 0, stream>>>(QKVb, Kc, Vt, O);

    gemm3<float><<<(M_ / 256) * (C_ / 128), 512, 0, stream>>>(O, Woutt, out, M_, C_, C_);
}